// Round 1
// baseline (406.581 us; speedup 1.0000x reference)
//
#include <hip/hip_runtime.h>

typedef unsigned short ushort_t;

// Problem constants (fixed by the reference)
// N=4000 nodes, E=60000 edges, M=16, C=64, H=64, HEADS=8, A=8, VC=8, CE=32, Z=90
// Composite-weight block layout (floats), per role stride RS:
//   WsWa [64*64] @0, WtWa [64*64] @4096, WeWa [32*64] @8192,
//   PsW [64*8] @10240, PtW [64*8] @10752, WeWvWo [32*8] @11264
constexpr int RS = 11520;

__device__ inline float bf2f(ushort_t u) {
    union { unsigned int i; float f; } v; v.i = ((unsigned int)u) << 16; return v.f;
}
__device__ inline ushort_t f2bf(float f) {
    union { float f; unsigned int i; } v; v.f = f;
    unsigned int b = v.i + 0x7FFFu + ((v.i >> 16) & 1u);  // RNE
    return (ushort_t)(b >> 16);
}

// ---------------------------------------------------------------------------
// Kernel A: weight composites.  grid = (6 tasks, 2 roles), 256 thr
// ---------------------------------------------------------------------------
__global__ __launch_bounds__(256) void k_composites(
    const float* __restrict__ Ws0, const float* __restrict__ Wt0, const float* __restrict__ We0,
    const float* __restrict__ Wa0, const float* __restrict__ Wv0, const float* __restrict__ Wo0,
    const float* __restrict__ Ws1, const float* __restrict__ Wt1, const float* __restrict__ We1,
    const float* __restrict__ Wa1, const float* __restrict__ Wv1, const float* __restrict__ Wo1,
    float* __restrict__ cmp)
{
    int task = blockIdx.x;   // 0..5
    int r    = blockIdx.y;   // 0..1
    const float* Ws = r ? Ws1 : Ws0;
    const float* Wt = r ? Wt1 : Wt0;
    const float* We = r ? We1 : We0;
    const float* Wa = r ? Wa1 : Wa0;
    const float* Wv = r ? Wv1 : Wv0;
    const float* Wo = r ? Wo1 : Wo0;
    float* base = cmp + r * RS;

    if (task == 0 || task == 1) {
        const float* L = task ? Wt : Ws;
        float* out = base + task * 4096;
        for (int idx = threadIdx.x; idx < 4096; idx += 256) {
            int c = idx >> 6, j = idx & 63;
            float a = 0.f;
            for (int k = 0; k < 64; ++k) a += L[c * 64 + k] * Wa[k * 64 + j];
            out[idx] = a;
        }
    } else if (task == 2) {
        float* out = base + 8192;
        for (int idx = threadIdx.x; idx < 2048; idx += 256) {
            int ce = idx >> 6, j = idx & 63;
            float a = 0.f;
            for (int k = 0; k < 64; ++k) a += We[ce * 64 + k] * Wa[k * 64 + j];
            out[idx] = a;
        }
    } else {
        // WvWo fold: WvWo[k,h] = sum_vc Wv[k, h*8+vc] * Wo[h*8+vc]
        const float* L = (task == 3) ? Ws : (task == 4) ? Wt : We;
        int rows = (task == 5) ? 32 : 64;
        float* out = base + ((task == 3) ? 10240 : (task == 4) ? 10752 : 11264);
        for (int idx = threadIdx.x; idx < rows * 8; idx += 256) {
            int c = idx >> 3, h = idx & 7;
            float a = 0.f;
            for (int k = 0; k < 64; ++k) {
                float wv = 0.f;
                #pragma unroll
                for (int aa = 0; aa < 8; ++aa) wv += Wv[k * 64 + h * 8 + aa] * Wo[h * 8 + aa];
                a += L[c * 64 + k] * wv;
            }
            out[idx] = a;
        }
    }
}

// ---------------------------------------------------------------------------
// Kernel B: per-node precompute.  grid = N blocks, 256 thr
//  srcA[n][r][m][j] = (x[n] @ WsWa_r)[m,j]   (bf16, both roles)
//  tgtA[n][m][j]    = (x[n] @ WtWa_sel)[m,j] (bf16, role = mask[n])
//  psrc[n][r][mrow 0..2][h] = (x[n] @ PsW_r)[1+mrow, h]
//  ptgt[n][mrow][h]         = (x[n] @ PtW_sel)[1+mrow, h]
// ---------------------------------------------------------------------------
__global__ __launch_bounds__(256) void k_node(
    const float* __restrict__ x, const int* __restrict__ mask,
    const float* __restrict__ cmp,
    float* __restrict__ psrc, float* __restrict__ ptgt,
    ushort_t* __restrict__ srcA, ushort_t* __restrict__ tgtA)
{
    int n = blockIdx.x;
    __shared__ float xb[1024];
    const float* xp = x + (size_t)n * 1024;
    for (int i = threadIdx.x; i < 1024; i += 256) xb[i] = xp[i];
    __syncthreads();

    int m  = threadIdx.x >> 4;   // 0..15 (M row)
    int jg = threadIdx.x & 15;   // 0..15 (j group of 4)
    int rsel = (mask[n] != 0);

    for (int task = 0; task < 3; ++task) {
        const float* W = cmp + ((task < 2) ? task * RS : rsel * RS + 4096);
        const float* Wp = W + jg * 4;
        float ax = 0.f, ay = 0.f, az = 0.f, aw = 0.f;
        for (int c = 0; c < 64; ++c) {
            float xs = xb[m * 64 + c];
            const float4 w = *(const float4*)(Wp + c * 64);
            ax += xs * w.x; ay += xs * w.y; az += xs * w.z; aw += xs * w.w;
        }
        ushort4 o; o.x = f2bf(ax); o.y = f2bf(ay); o.z = f2bf(az); o.w = f2bf(aw);
        ushort_t* dp = (task < 2)
            ? (srcA + (size_t)n * 2048 + task * 1024 + m * 64 + jg * 4)
            : (tgtA + (size_t)n * 1024 + m * 64 + jg * 4);
        *(ushort4*)dp = o;
    }

    int t = threadIdx.x;
    if (t < 48) {                 // psrc, both roles
        int r = t / 24, rem = t % 24;
        int mm = 1 + rem / 8, h = rem & 7;
        const float* W = cmp + r * RS + 10240;
        float a = 0.f;
        for (int c = 0; c < 64; ++c) a += xb[mm * 64 + c] * W[c * 8 + h];
        psrc[(size_t)n * 48 + t] = a;
    } else if (t < 72) {          // ptgt, selected role
        int tt = t - 48;
        int mm = 1 + tt / 8, h = tt & 7;
        const float* W = cmp + rsel * RS + 10752;
        float a = 0.f;
        for (int c = 0; c < 64; ++c) a += xb[mm * 64 + c] * W[c * 8 + h];
        ptgt[(size_t)n * 24 + tt] = a;
    }
}

// ---------------------------------------------------------------------------
// Kernel C: per-edge logits + exp + denominator atomics.  one wave per edge
// ---------------------------------------------------------------------------
__global__ __launch_bounds__(256) void k_logits(
    const int* __restrict__ ei, const float* __restrict__ dist,
    const int* __restrict__ zn, const int* __restrict__ mask,
    const float* __restrict__ wig, const float* __restrict__ cmp,
    const float* __restrict__ embs0, const float* __restrict__ embt0, const float* __restrict__ wd0,
    const float* __restrict__ embs1, const float* __restrict__ embt1, const float* __restrict__ wd1,
    const float* __restrict__ va0, const float* __restrict__ va1,
    const ushort_t* __restrict__ srcA, const ushort_t* __restrict__ tgtA,
    float* __restrict__ den, float* __restrict__ exb, float* __restrict__ ejb, int E)
{
    int wv = threadIdx.x >> 6, j = threadIdx.x & 63;
    int e = blockIdx.x * 4 + wv;
    if (e >= E) return;
    int src = ei[e], dst = ei[E + e];
    int r = (mask[dst] != 0);
    float d = dist[e];
    int zs = zn[src], zt = zn[dst];

    // edge scalar embedding e_scal (32 values, computed in lanes via j&31)
    float es;
    {
        int ce = j & 31;
        float z = r ? (d * wd1[ce] + embs1[zs * 32 + ce] + embt1[zt * 32 + ce])
                    : (d * wd0[ce] + embs0[zs * 32 + ce] + embt0[zt * 32 + ce]);
        es = z / (1.f + __expf(-z));   // silu
    }

    const float* WeWa   = cmp + r * RS + 8192;
    const float* WeWvWo = cmp + r * RS + 11264;
    int h8 = j & 7;
    float f0a = 0.f, ej = 0.f;
    #pragma unroll
    for (int ce = 0; ce < 32; ++ce) {
        float ev = __shfl(es, ce, 64);
        f0a += ev * WeWa[ce * 64 + j];
        ej  += ev * WeWvWo[ce * 8 + h8];
    }

    // f0a[j] += sum_n D[0,n] * (ysa[src][n,j] + yta[dst][n,j])
    const ushort_t* sp = srcA + (size_t)src * 2048 + r * 1024 + j;
    const ushort_t* tp = tgtA + (size_t)dst * 1024 + j;
    const float* w0 = wig + (size_t)e * 256;
    #pragma unroll
    for (int n = 0; n < 16; ++n) {
        float sv = bf2f(sp[n * 64]) + bf2f(tp[n * 64]);
        f0a += w0[n] * sv;
    }

    float la = f0a > 0.f ? f0a : 0.2f * f0a;           // leaky_relu(0.2)
    float val = la * (r ? va1[j] : va0[j]);
    val += __shfl_xor(val, 1);
    val += __shfl_xor(val, 2);
    val += __shfl_xor(val, 4);                          // logit per 8-lane group
    float ex = __expf(val);                             // no-max softmax (logits bounded)
    if (h8 == 0) {
        atomicAdd(&den[dst * 8 + (j >> 3)], ex);
        exb[(size_t)e * 8 + (j >> 3)] = ex;
    }
    if (j < 8) ejb[(size_t)e * 8 + j] = ej;
}

// ---------------------------------------------------------------------------
// Kernel D: per-edge value + scatter.  8 lanes per edge
//   out[dst, m-1] += sum_h alpha[h]*(Ps[src]+Pt[dst])[m,h] + D[0,m]*sum_h alpha[h]*einjWo[h]
// ---------------------------------------------------------------------------
__global__ __launch_bounds__(256) void k_scatter(
    const int* __restrict__ ei, const int* __restrict__ mask,
    const float* __restrict__ wig,
    const float* __restrict__ psrc, const float* __restrict__ ptgt,
    const float* __restrict__ exb, const float* __restrict__ ejb,
    const float* __restrict__ den, float* __restrict__ out, int E)
{
    int t = threadIdx.x;
    int g = t >> 3, h = t & 7;
    int e = blockIdx.x * 32 + g;
    if (e >= E) return;
    int src = ei[e], dst = ei[E + e];
    int r = (mask[dst] != 0);
    float alpha = exb[(size_t)e * 8 + h] / (den[dst * 8 + h] + 1e-9f);
    const float* ps = psrc + (size_t)src * 48 + r * 24;
    const float* pt = ptgt + (size_t)dst * 24;
    float s0 = alpha * (ps[h]      + pt[h]);
    float s1 = alpha * (ps[8 + h]  + pt[8 + h]);
    float s2 = alpha * (ps[16 + h] + pt[16 + h]);
    float se = alpha * ejb[(size_t)e * 8 + h];
    #pragma unroll
    for (int off = 1; off < 8; off <<= 1) {
        s0 += __shfl_xor(s0, off);
        s1 += __shfl_xor(s1, off);
        s2 += __shfl_xor(s2, off);
        se += __shfl_xor(se, off);
    }
    if (h == 0) {
        const float* w0 = wig + (size_t)e * 256;   // D[0, :]
        atomicAdd(&out[dst * 3 + 0], s0 + w0[1] * se);
        atomicAdd(&out[dst * 3 + 1], s1 + w0[2] * se);
        atomicAdd(&out[dst * 3 + 2], s2 + w0[3] * se);
    }
}

// ---------------------------------------------------------------------------
extern "C" void kernel_launch(void* const* d_in, const int* in_sizes, int n_in,
                              void* d_out, int out_size, void* d_ws, size_t ws_size,
                              hipStream_t stream) {
    const float* x    = (const float*)d_in[0];
    const int*   zn   = (const int*)d_in[1];
    const float* dist = (const float*)d_in[2];
    const int*   ei   = (const int*)d_in[3];
    const int*   mask = (const int*)d_in[4];
    const float* wig  = (const float*)d_in[5];
    // per role: emb_s, emb_t, w_d, We, Ws, Wt, Wa, va, Wv, Wo
    const float* fs[10]; const float* dn[10];
    for (int i = 0; i < 10; ++i) { fs[i] = (const float*)d_in[6 + i]; dn[i] = (const float*)d_in[16 + i]; }

    int N = in_sizes[1];   // atomic_numbers count
    int E = in_sizes[2];   // edge_distance count

    // workspace carve-up (fp32 unless noted)
    float* cmp  = (float*)d_ws;                    // 2*RS = 23040 floats
    float* den  = cmp + 2 * RS;                    // N*8
    float* exb  = den + (size_t)N * 8;             // E*8
    float* ejb  = exb + (size_t)E * 8;             // E*8
    float* psrc = ejb + (size_t)E * 8;             // N*48
    float* ptgt = psrc + (size_t)N * 48;           // N*24
    ushort_t* srcA = (ushort_t*)(ptgt + (size_t)N * 24);  // N*2048 bf16
    ushort_t* tgtA = srcA + (size_t)N * 2048;             // N*1024 bf16
    // total ~29.8 MB

    hipMemsetAsync(d_out, 0, (size_t)out_size * sizeof(float), stream);
    hipMemsetAsync(den, 0, (size_t)N * 8 * sizeof(float), stream);

    k_composites<<<dim3(6, 2), 256, 0, stream>>>(
        fs[4], fs[5], fs[3], fs[6], fs[8], fs[9],
        dn[4], dn[5], dn[3], dn[6], dn[8], dn[9], cmp);

    k_node<<<N, 256, 0, stream>>>(x, mask, cmp, psrc, ptgt, srcA, tgtA);

    k_logits<<<(E + 3) / 4, 256, 0, stream>>>(
        ei, dist, zn, mask, wig, cmp,
        fs[0], fs[1], fs[2], dn[0], dn[1], dn[2],
        fs[7], dn[7], srcA, tgtA, den, exb, ejb, E);

    k_scatter<<<(E + 31) / 32, 256, 0, stream>>>(
        ei, mask, wig, psrc, ptgt, exb, ejb, den, (float*)d_out, E);
}

// Round 2
// 260.876 us; speedup vs baseline: 1.5585x; 1.5585x over previous
//
#include <hip/hip_runtime.h>

typedef unsigned short ushort_t;
typedef __attribute__((ext_vector_type(8))) short short8;   // 8 x bf16 (MFMA A/B frag)
typedef __attribute__((ext_vector_type(4))) float floatx4;  // MFMA C/D frag

// Problem constants (fixed by the reference)
// N=4000 nodes, E=60000 edges, M=16, C=64, H=64, HEADS=8, A=8, VC=8, CE=32, Z=90
// Composite-weight block layout (floats), per role stride RS:
//   WsWa [64*64] @0, WtWa [64*64] @4096, WeWa [32*64] @8192,
//   PsW [64*8] @10240, PtW [64*8] @10752, WeWvWo [32*8] @11264
constexpr int RS = 11520;

__device__ inline float bf2f(ushort_t u) {
    union { unsigned int i; float f; } v; v.i = ((unsigned int)u) << 16; return v.f;
}
__device__ inline ushort_t f2bf(float f) {
    union { float f; unsigned int i; } v; v.f = f;
    unsigned int b = v.i + 0x7FFFu + ((v.i >> 16) & 1u);  // RNE
    return (ushort_t)(b >> 16);
}

// ---------------------------------------------------------------------------
// Kernel A: weight composites.  grid = (6 tasks, 2 roles), 256 thr
// ---------------------------------------------------------------------------
__global__ __launch_bounds__(256) void k_composites(
    const float* __restrict__ Ws0, const float* __restrict__ Wt0, const float* __restrict__ We0,
    const float* __restrict__ Wa0, const float* __restrict__ Wv0, const float* __restrict__ Wo0,
    const float* __restrict__ Ws1, const float* __restrict__ Wt1, const float* __restrict__ We1,
    const float* __restrict__ Wa1, const float* __restrict__ Wv1, const float* __restrict__ Wo1,
    float* __restrict__ cmp)
{
    int task = blockIdx.x;   // 0..5
    int r    = blockIdx.y;   // 0..1
    const float* Ws = r ? Ws1 : Ws0;
    const float* Wt = r ? Wt1 : Wt0;
    const float* We = r ? We1 : We0;
    const float* Wa = r ? Wa1 : Wa0;
    const float* Wv = r ? Wv1 : Wv0;
    const float* Wo = r ? Wo1 : Wo0;
    float* base = cmp + r * RS;

    if (task == 0 || task == 1) {
        const float* L = task ? Wt : Ws;
        float* out = base + task * 4096;
        for (int idx = threadIdx.x; idx < 4096; idx += 256) {
            int c = idx >> 6, j = idx & 63;
            float a = 0.f;
            for (int k = 0; k < 64; ++k) a += L[c * 64 + k] * Wa[k * 64 + j];
            out[idx] = a;
        }
    } else if (task == 2) {
        float* out = base + 8192;
        for (int idx = threadIdx.x; idx < 2048; idx += 256) {
            int ce = idx >> 6, j = idx & 63;
            float a = 0.f;
            for (int k = 0; k < 64; ++k) a += We[ce * 64 + k] * Wa[k * 64 + j];
            out[idx] = a;
        }
    } else {
        // WvWo fold: WvWo[k,h] = sum_vc Wv[k, h*8+vc] * Wo[h*8+vc]
        const float* L = (task == 3) ? Ws : (task == 4) ? Wt : We;
        int rows = (task == 5) ? 32 : 64;
        float* out = base + ((task == 3) ? 10240 : (task == 4) ? 10752 : 11264);
        for (int idx = threadIdx.x; idx < rows * 8; idx += 256) {
            int c = idx >> 3, h = idx & 7;
            float a = 0.f;
            for (int k = 0; k < 64; ++k) {
                float wv = 0.f;
                #pragma unroll
                for (int aa = 0; aa < 8; ++aa) wv += Wv[k * 64 + h * 8 + aa] * Wo[h * 8 + aa];
                a += L[c * 64 + k] * wv;
            }
            out[idx] = a;
        }
    }
}

// ---------------------------------------------------------------------------
// Kernel B: per-node precompute via MFMA, one wave per node (grid-stride).
// All weight B-fragments live in VGPRs for the wave's lifetime (no LDS,
// no per-node weight traffic). Layouts (HW-verified, see guide §3/§5):
//   A[m=lane&15][k=(lane>>4)*8+j],  B[k=(lane>>4)*8+j][n=lane&15],
//   C/D: col=lane&15, row=(lane>>4)*4+reg.
// ---------------------------------------------------------------------------
__device__ inline short8 bfragW(const float* __restrict__ W, int colBase, int kBase,
                                int q, int n) {
    short8 f;
    #pragma unroll
    for (int j = 0; j < 8; ++j)
        f[j] = (short)f2bf(W[(kBase + q * 8 + j) * 64 + colBase + n]);
    return f;
}
__device__ inline short8 bfragP(const float* __restrict__ P0, const float* __restrict__ P1,
                                int kBase, int q, int n) {
    const float* P = (n < 8) ? P0 : P1;
    int c = n & 7;
    short8 f;
    #pragma unroll
    for (int j = 0; j < 8; ++j)
        f[j] = (short)f2bf(P[(kBase + q * 8 + j) * 8 + c]);
    return f;
}

#define MFMA(a, b, c) __builtin_amdgcn_mfma_f32_16x16x32_bf16((a), (b), (c), 0, 0, 0)

__global__ __launch_bounds__(256, 2) void k_node(
    const float* __restrict__ x, const int* __restrict__ mask,
    const float* __restrict__ cmp,
    float* __restrict__ psrc, float* __restrict__ ptgt,
    ushort_t* __restrict__ srcA, ushort_t* __restrict__ tgtA,
    int N, int totWaves)
{
    int wid  = (int)((blockIdx.x * blockDim.x + threadIdx.x) >> 6);
    int lane = threadIdx.x & 63;
    int q    = lane >> 4;     // quad 0..3
    int n16  = lane & 15;     // 0..15

    // --- stage all weight fragments into registers (once per wave) ---
    short8 Bs0[4][2], Bs1[4][2], Bt0[4][2], Bt1[4][2];
    #pragma unroll
    for (int t = 0; t < 4; ++t) {
        #pragma unroll
        for (int kh = 0; kh < 2; ++kh) {
            Bs0[t][kh] = bfragW(cmp,             t * 16, kh * 32, q, n16);
            Bs1[t][kh] = bfragW(cmp + RS,        t * 16, kh * 32, q, n16);
            Bt0[t][kh] = bfragW(cmp + 4096,      t * 16, kh * 32, q, n16);
            Bt1[t][kh] = bfragW(cmp + RS + 4096, t * 16, kh * 32, q, n16);
        }
    }
    short8 Bp[2], Bq[2];
    #pragma unroll
    for (int kh = 0; kh < 2; ++kh) {
        Bp[kh] = bfragP(cmp + 10240, cmp + RS + 10240, kh * 32, q, n16);
        Bq[kh] = bfragP(cmp + 10752, cmp + RS + 10752, kh * 32, q, n16);
    }

    const floatx4 zero = {0.f, 0.f, 0.f, 0.f};

    for (int nd = wid; nd < N; nd += totWaves) {
        // --- A fragments: x[nd] is [16,64] fp32, row m=n16, k base q*8 ---
        const float* xp = x + (size_t)nd * 1024 + n16 * 64 + q * 8;
        float4 v0 = *(const float4*)(xp);
        float4 v1 = *(const float4*)(xp + 4);
        float4 v2 = *(const float4*)(xp + 32);
        float4 v3 = *(const float4*)(xp + 36);
        short8 a0, a1;
        a0[0] = (short)f2bf(v0.x); a0[1] = (short)f2bf(v0.y);
        a0[2] = (short)f2bf(v0.z); a0[3] = (short)f2bf(v0.w);
        a0[4] = (short)f2bf(v1.x); a0[5] = (short)f2bf(v1.y);
        a0[6] = (short)f2bf(v1.z); a0[7] = (short)f2bf(v1.w);
        a1[0] = (short)f2bf(v2.x); a1[1] = (short)f2bf(v2.y);
        a1[2] = (short)f2bf(v2.z); a1[3] = (short)f2bf(v2.w);
        a1[4] = (short)f2bf(v3.x); a1[5] = (short)f2bf(v3.y);
        a1[6] = (short)f2bf(v3.z); a1[7] = (short)f2bf(v3.w);

        int rsel = (mask[nd] != 0);

        // --- srcA, both roles ---
        {
            floatx4 c0 = zero, c1 = zero, c2 = zero, c3 = zero;
            c0 = MFMA(a0, Bs0[0][0], c0); c0 = MFMA(a1, Bs0[0][1], c0);
            c1 = MFMA(a0, Bs0[1][0], c1); c1 = MFMA(a1, Bs0[1][1], c1);
            c2 = MFMA(a0, Bs0[2][0], c2); c2 = MFMA(a1, Bs0[2][1], c2);
            c3 = MFMA(a0, Bs0[3][0], c3); c3 = MFMA(a1, Bs0[3][1], c3);
            ushort_t* sp = srcA + (size_t)nd * 2048 + (q * 4) * 64 + n16;
            #pragma unroll
            for (int rr = 0; rr < 4; ++rr) {
                sp[rr * 64 +  0] = f2bf(c0[rr]);
                sp[rr * 64 + 16] = f2bf(c1[rr]);
                sp[rr * 64 + 32] = f2bf(c2[rr]);
                sp[rr * 64 + 48] = f2bf(c3[rr]);
            }
        }
        {
            floatx4 c0 = zero, c1 = zero, c2 = zero, c3 = zero;
            c0 = MFMA(a0, Bs1[0][0], c0); c0 = MFMA(a1, Bs1[0][1], c0);
            c1 = MFMA(a0, Bs1[1][0], c1); c1 = MFMA(a1, Bs1[1][1], c1);
            c2 = MFMA(a0, Bs1[2][0], c2); c2 = MFMA(a1, Bs1[2][1], c2);
            c3 = MFMA(a0, Bs1[3][0], c3); c3 = MFMA(a1, Bs1[3][1], c3);
            ushort_t* sp = srcA + (size_t)nd * 2048 + 1024 + (q * 4) * 64 + n16;
            #pragma unroll
            for (int rr = 0; rr < 4; ++rr) {
                sp[rr * 64 +  0] = f2bf(c0[rr]);
                sp[rr * 64 + 16] = f2bf(c1[rr]);
                sp[rr * 64 + 32] = f2bf(c2[rr]);
                sp[rr * 64 + 48] = f2bf(c3[rr]);
            }
        }

        // --- tgtA, selected role (wave-uniform branch; constant indices only) ---
        {
            floatx4 c0 = zero, c1 = zero, c2 = zero, c3 = zero;
            if (rsel) {
                c0 = MFMA(a0, Bt1[0][0], c0); c0 = MFMA(a1, Bt1[0][1], c0);
                c1 = MFMA(a0, Bt1[1][0], c1); c1 = MFMA(a1, Bt1[1][1], c1);
                c2 = MFMA(a0, Bt1[2][0], c2); c2 = MFMA(a1, Bt1[2][1], c2);
                c3 = MFMA(a0, Bt1[3][0], c3); c3 = MFMA(a1, Bt1[3][1], c3);
            } else {
                c0 = MFMA(a0, Bt0[0][0], c0); c0 = MFMA(a1, Bt0[0][1], c0);
                c1 = MFMA(a0, Bt0[1][0], c1); c1 = MFMA(a1, Bt0[1][1], c1);
                c2 = MFMA(a0, Bt0[2][0], c2); c2 = MFMA(a1, Bt0[2][1], c2);
                c3 = MFMA(a0, Bt0[3][0], c3); c3 = MFMA(a1, Bt0[3][1], c3);
            }
            ushort_t* tp = tgtA + (size_t)nd * 1024 + (q * 4) * 64 + n16;
            #pragma unroll
            for (int rr = 0; rr < 4; ++rr) {
                tp[rr * 64 +  0] = f2bf(c0[rr]);
                tp[rr * 64 + 16] = f2bf(c1[rr]);
                tp[rr * 64 + 32] = f2bf(c2[rr]);
                tp[rr * 64 + 48] = f2bf(c3[rr]);
            }
        }

        // --- Ps (both roles in one 16-col tile) and Pt (selected role) ---
        {
            floatx4 cp = zero;
            cp = MFMA(a0, Bp[0], cp); cp = MFMA(a1, Bp[1], cp);
            if (q == 0) {  // rows 1..3 live in regs 1..3 of quad 0
                int r = n16 >> 3, h = n16 & 7;
                float* pp = psrc + (size_t)nd * 48 + r * 24 + h;
                pp[0]  = cp[1];
                pp[8]  = cp[2];
                pp[16] = cp[3];
            }
            floatx4 cq = zero;
            cq = MFMA(a0, Bq[0], cq); cq = MFMA(a1, Bq[1], cq);
            if (q == 0 && (n16 >> 3) == rsel) {
                int h = n16 & 7;
                float* pp = ptgt + (size_t)nd * 24 + h;
                pp[0]  = cq[1];
                pp[8]  = cq[2];
                pp[16] = cq[3];
            }
        }
    }
}

// ---------------------------------------------------------------------------
// Kernel C: per-edge logits + exp + denominator atomics.  one wave per edge
// ---------------------------------------------------------------------------
__global__ __launch_bounds__(256) void k_logits(
    const int* __restrict__ ei, const float* __restrict__ dist,
    const int* __restrict__ zn, const int* __restrict__ mask,
    const float* __restrict__ wig, const float* __restrict__ cmp,
    const float* __restrict__ embs0, const float* __restrict__ embt0, const float* __restrict__ wd0,
    const float* __restrict__ embs1, const float* __restrict__ embt1, const float* __restrict__ wd1,
    const float* __restrict__ va0, const float* __restrict__ va1,
    const ushort_t* __restrict__ srcA, const ushort_t* __restrict__ tgtA,
    float* __restrict__ den, float* __restrict__ exb, float* __restrict__ ejb, int E)
{
    int wv = threadIdx.x >> 6, j = threadIdx.x & 63;
    int e = blockIdx.x * 4 + wv;
    if (e >= E) return;
    int src = ei[e], dst = ei[E + e];
    int r = (mask[dst] != 0);
    float d = dist[e];
    int zs = zn[src], zt = zn[dst];

    // edge scalar embedding e_scal (32 values, computed in lanes via j&31)
    float es;
    {
        int ce = j & 31;
        float z = r ? (d * wd1[ce] + embs1[zs * 32 + ce] + embt1[zt * 32 + ce])
                    : (d * wd0[ce] + embs0[zs * 32 + ce] + embt0[zt * 32 + ce]);
        es = z / (1.f + __expf(-z));   // silu
    }

    const float* WeWa   = cmp + r * RS + 8192;
    const float* WeWvWo = cmp + r * RS + 11264;
    int h8 = j & 7;
    float f0a = 0.f, ej = 0.f;
    #pragma unroll
    for (int ce = 0; ce < 32; ++ce) {
        float ev = __shfl(es, ce, 64);
        f0a += ev * WeWa[ce * 64 + j];
        ej  += ev * WeWvWo[ce * 8 + h8];
    }

    // f0a[j] += sum_n D[0,n] * (ysa[src][n,j] + yta[dst][n,j])
    const ushort_t* sp = srcA + (size_t)src * 2048 + r * 1024 + j;
    const ushort_t* tp = tgtA + (size_t)dst * 1024 + j;
    const float* w0 = wig + (size_t)e * 256;
    #pragma unroll
    for (int n = 0; n < 16; ++n) {
        float sv = bf2f(sp[n * 64]) + bf2f(tp[n * 64]);
        f0a += w0[n] * sv;
    }

    float la = f0a > 0.f ? f0a : 0.2f * f0a;           // leaky_relu(0.2)
    float val = la * (r ? va1[j] : va0[j]);
    val += __shfl_xor(val, 1);
    val += __shfl_xor(val, 2);
    val += __shfl_xor(val, 4);                          // logit per 8-lane group
    float ex = __expf(val);                             // no-max softmax (logits bounded)
    if (h8 == 0) {
        atomicAdd(&den[dst * 8 + (j >> 3)], ex);
        exb[(size_t)e * 8 + (j >> 3)] = ex;
    }
    if (j < 8) ejb[(size_t)e * 8 + j] = ej;
}

// ---------------------------------------------------------------------------
// Kernel D: per-edge value + scatter.  8 lanes per edge
//   out[dst, m-1] += sum_h alpha[h]*(Ps[src]+Pt[dst])[m,h] + D[0,m]*sum_h alpha[h]*einjWo[h]
// ---------------------------------------------------------------------------
__global__ __launch_bounds__(256) void k_scatter(
    const int* __restrict__ ei, const int* __restrict__ mask,
    const float* __restrict__ wig,
    const float* __restrict__ psrc, const float* __restrict__ ptgt,
    const float* __restrict__ exb, const float* __restrict__ ejb,
    const float* __restrict__ den, float* __restrict__ out, int E)
{
    int t = threadIdx.x;
    int g = t >> 3, h = t & 7;
    int e = blockIdx.x * 32 + g;
    if (e >= E) return;
    int src = ei[e], dst = ei[E + e];
    int r = (mask[dst] != 0);
    float alpha = exb[(size_t)e * 8 + h] / (den[dst * 8 + h] + 1e-9f);
    const float* ps = psrc + (size_t)src * 48 + r * 24;
    const float* pt = ptgt + (size_t)dst * 24;
    float s0 = alpha * (ps[h]      + pt[h]);
    float s1 = alpha * (ps[8 + h]  + pt[8 + h]);
    float s2 = alpha * (ps[16 + h] + pt[16 + h]);
    float se = alpha * ejb[(size_t)e * 8 + h];
    #pragma unroll
    for (int off = 1; off < 8; off <<= 1) {
        s0 += __shfl_xor(s0, off);
        s1 += __shfl_xor(s1, off);
        s2 += __shfl_xor(s2, off);
        se += __shfl_xor(se, off);
    }
    if (h == 0) {
        const float* w0 = wig + (size_t)e * 256;   // D[0, :]
        atomicAdd(&out[dst * 3 + 0], s0 + w0[1] * se);
        atomicAdd(&out[dst * 3 + 1], s1 + w0[2] * se);
        atomicAdd(&out[dst * 3 + 2], s2 + w0[3] * se);
    }
}

// ---------------------------------------------------------------------------
extern "C" void kernel_launch(void* const* d_in, const int* in_sizes, int n_in,
                              void* d_out, int out_size, void* d_ws, size_t ws_size,
                              hipStream_t stream) {
    const float* x    = (const float*)d_in[0];
    const int*   zn   = (const int*)d_in[1];
    const float* dist = (const float*)d_in[2];
    const int*   ei   = (const int*)d_in[3];
    const int*   mask = (const int*)d_in[4];
    const float* wig  = (const float*)d_in[5];
    // per role: emb_s, emb_t, w_d, We, Ws, Wt, Wa, va, Wv, Wo
    const float* fs[10]; const float* dn[10];
    for (int i = 0; i < 10; ++i) { fs[i] = (const float*)d_in[6 + i]; dn[i] = (const float*)d_in[16 + i]; }

    int N = in_sizes[1];   // atomic_numbers count
    int E = in_sizes[2];   // edge_distance count

    // workspace carve-up (fp32 unless noted)
    float* cmp  = (float*)d_ws;                    // 2*RS = 23040 floats
    float* den  = cmp + 2 * RS;                    // N*8
    float* exb  = den + (size_t)N * 8;             // E*8
    float* ejb  = exb + (size_t)E * 8;             // E*8
    float* psrc = ejb + (size_t)E * 8;             // N*48
    float* ptgt = psrc + (size_t)N * 48;           // N*24
    ushort_t* srcA = (ushort_t*)(ptgt + (size_t)N * 24);  // N*2048 bf16
    ushort_t* tgtA = srcA + (size_t)N * 2048;             // N*1024 bf16
    // total ~29.8 MB

    hipMemsetAsync(d_out, 0, (size_t)out_size * sizeof(float), stream);
    hipMemsetAsync(den, 0, (size_t)N * 8 * sizeof(float), stream);

    k_composites<<<dim3(6, 2), 256, 0, stream>>>(
        fs[4], fs[5], fs[3], fs[6], fs[8], fs[9],
        dn[4], dn[5], dn[3], dn[6], dn[8], dn[9], cmp);

    int nodeBlocks = 512;
    int totWaves = nodeBlocks * (256 / 64);
    k_node<<<nodeBlocks, 256, 0, stream>>>(x, mask, cmp, psrc, ptgt, srcA, tgtA, N, totWaves);

    k_logits<<<(E + 3) / 4, 256, 0, stream>>>(
        ei, dist, zn, mask, wig, cmp,
        fs[0], fs[1], fs[2], dn[0], dn[1], dn[2],
        fs[7], dn[7], srcA, tgtA, den, exb, ejb, E);

    k_scatter<<<(E + 31) / 32, 256, 0, stream>>>(
        ei, mask, wig, psrc, ptgt, exb, ejb, den, (float*)d_out, E);
}